// Round 13
// baseline (171.642 us; speedup 1.0000x reference)
//
#include <hip/hip_runtime.h>

using bf16   = __bf16;
using bf16x4 = __bf16 __attribute__((ext_vector_type(4)));
using bf16x8 = __bf16 __attribute__((ext_vector_type(8)));
using f32x4  = float __attribute__((ext_vector_type(4)));
using f32x16 = float __attribute__((ext_vector_type(16)));
using u32x2  = unsigned int __attribute__((ext_vector_type(2)));
using u32x4  = unsigned int __attribute__((ext_vector_type(4)));

#define L_SEQ  2048
#define DMODEL 2048
#define NQH    32
#define NKVH   8
#define HDIM   64
#define QKV_N  3072   // NQH*HDIM + 2*NKVH*HDIM

// fragment-ordered K/V: per kv-head, 64 key-blocks of 32; each block = 4 frags
// of (64 lanes x 8 elems) = 2048 elems; per-head stride:
#define KVF_HSTRIDE (64 * 4 * 64 * 8)   // 131072 elems = 256 KiB

// ---------- helpers ----------
__device__ __forceinline__ void gload_lds16(const void* g, void* lds) {
  __builtin_amdgcn_global_load_lds((__attribute__((address_space(1))) void*)(g),
                                   (__attribute__((address_space(3))) void*)(lds),
                                   16, 0, 0);
}

__device__ __forceinline__ unsigned pack2(float a, float b) {
  union { bf16 h[2]; unsigned u; } x;
  x.h[0] = (bf16)a; x.h[1] = (bf16)b;
  return x.u;
}

// assemble the PV B-fragment from 8 per-lane P values (swapped layout)
__device__ __forceinline__ bf16x8 make_pfrag(float p0, float p1, float p2, float p3,
                                             float p4, float p5, float p6, float p7,
                                             int hi) {
  const unsigned W0 = pack2(p0, p1);
  const unsigned W1 = pack2(p2, p3);
  const unsigned W2 = pack2(p4, p5);
  const unsigned W3 = pack2(p6, p7);
  u32x4 pw;
#if __has_builtin(__builtin_amdgcn_permlane32_swap)
  {
    using i32x2 = int __attribute__((ext_vector_type(2)));
    const i32x2 r02 = __builtin_amdgcn_permlane32_swap((int)W0, (int)W2, false, false);
    const i32x2 r13 = __builtin_amdgcn_permlane32_swap((int)W1, (int)W3, false, false);
    pw = u32x4{ (unsigned)r02[0], (unsigned)r13[0], (unsigned)r02[1], (unsigned)r13[1] };
  }
#else
  {
    const unsigned X0 = (unsigned)__shfl_xor((int)W0, 32);
    const unsigned X1 = (unsigned)__shfl_xor((int)W1, 32);
    const unsigned X2 = (unsigned)__shfl_xor((int)W2, 32);
    const unsigned X3 = (unsigned)__shfl_xor((int)W3, 32);
    pw = u32x4{ hi ? X2 : W0, hi ? X3 : W1, hi ? W2 : X0, hi ? W3 : X1 };
  }
#endif
  return __builtin_bit_cast(bf16x8, pw);
}

// cumulative chunk count before q-superblock Qb (64 q-rows each; chunks of 16
// key-subtiles; Qb needs 2*Qb+2 subtiles)
__device__ __forceinline__ int chunk_base64(int Qb) {
  return (Qb < 8)  ? Qb
       : (Qb < 16) ? 8  + 2 * (Qb - 8)
       : (Qb < 24) ? 24 + 3 * (Qb - 16)
                   : 48 + 4 * (Qb - 24);
}

// ---------- fused fp32 -> bf16 convert (x, w_qkv, w_out in one launch) ----------
#define N4_X  (L_SEQ * DMODEL / 4)          // 1048576
#define N4_WQ (QKV_N * DMODEL / 4)          // 1572864
#define N4_WO (DMODEL * DMODEL / 4)         // 1048576
__global__ void cvt3_f32_bf16(const float* __restrict__ x, const float* __restrict__ wq,
                              const float* __restrict__ wo, bf16* __restrict__ xb,
                              bf16* __restrict__ wqb, bf16* __restrict__ wob) {
  const long stride = (long)gridDim.x * blockDim.x;
  const long ntot = N4_X + N4_WQ + N4_WO;
  for (long i = (long)blockIdx.x * blockDim.x + threadIdx.x; i < ntot; i += stride) {
    const float* src; bf16* dst; long j;
    if (i < N4_X)               { src = x;  dst = xb;  j = i; }
    else if (i < N4_X + N4_WQ)  { src = wq; dst = wqb; j = i - N4_X; }
    else                        { src = wo; dst = wob; j = i - N4_X - N4_WQ; }
    const float4 v = reinterpret_cast<const float4*>(src)[j];
    bf16x4 o = { (bf16)v.x, (bf16)v.y, (bf16)v.z, (bf16)v.w };
    reinterpret_cast<bf16x4*>(dst)[j] = o;
  }
}

// ---------- bf16 GEMM: C(MxN) = A(MxK) * B(NxK)^T, 128x64 tile, BK=64 ----------
// 2 waves per block; each wave computes the FULL 64x64 half-tile.
// Split-K via gridDim.z: block z covers K-range [z*K/gz, (z+1)*K/gz), writing
// its partial to C + z*M*N. gz=1 -> plain GEMM.
template <typename OutT>
__global__ __launch_bounds__(128)
void gemm_bt(const bf16* __restrict__ A, const bf16* __restrict__ B,
             OutT* __restrict__ C, int M, int N, int K) {
  __shared__ bf16 As[128 * 64];
  __shared__ bf16 Bs[64 * 64];
  const int tid = threadIdx.x;
  const int w = tid >> 6, l = tid & 63;
  const int lq = l & 15, lg = l >> 4;
  const long m0 = (long)blockIdx.y * 128;
  const long n0 = (long)blockIdx.x * 64;
  const int ks = K / gridDim.z;
  const int kb = blockIdx.z * ks;
  C += (long)blockIdx.z * M * N;

  const int lrow = l >> 3;                   // row within 8-row group (0..7)
  const int scol = ((l & 7) ^ lrow) << 3;    // pre-swizzled global element column

  f32x4 acc[4][4];
#pragma unroll
  for (int i = 0; i < 4; ++i)
#pragma unroll
    for (int j = 0; j < 4; ++j) acc[i][j] = f32x4{0.f, 0.f, 0.f, 0.f};

  for (int k0 = kb; k0 < kb + ks; k0 += 64) {
#pragma unroll
    for (int i = 0; i < 8; ++i) {
      const int r0 = (i * 2 + w) * 8;
      gload_lds16(A + (m0 + r0 + lrow) * (long)K + k0 + scol, &As[r0 * 64]);
    }
#pragma unroll
    for (int i = 0; i < 4; ++i) {
      const int r0 = (i * 2 + w) * 8;
      gload_lds16(B + (n0 + r0 + lrow) * (long)K + k0 + scol, &Bs[r0 * 64]);
    }
    __syncthreads();
#pragma unroll
    for (int kk = 0; kk < 2; ++kk) {
      bf16x8 af[4], bfr[4];
#pragma unroll
      for (int t = 0; t < 4; ++t) {
        const int rowA = w * 64 + t * 16 + lq;
        const int blkA = (kk * 4 + lg) ^ (rowA & 7);
        af[t] = *reinterpret_cast<const bf16x8*>(&As[rowA * 64 + blkA * 8]);
        const int rowB = t * 16 + lq;
        const int blkB = (kk * 4 + lg) ^ (rowB & 7);
        bfr[t] = *reinterpret_cast<const bf16x8*>(&Bs[rowB * 64 + blkB * 8]);
      }
#pragma unroll
      for (int mt = 0; mt < 4; ++mt)
#pragma unroll
        for (int nt = 0; nt < 4; ++nt)
          acc[mt][nt] = __builtin_amdgcn_mfma_f32_16x16x32_bf16(af[mt], bfr[nt], acc[mt][nt], 0, 0, 0);
    }
    __syncthreads();
  }

#pragma unroll
  for (int mt = 0; mt < 4; ++mt)
#pragma unroll
    for (int r = 0; r < 4; ++r) {
      const long row = m0 + w * 64 + mt * 16 + lg * 4 + r;
#pragma unroll
      for (int nt = 0; nt < 4; ++nt) {
        const long col = n0 + nt * 16 + lq;
        C[row * (long)N + col] = (OutT)acc[mt][nt][r];
      }
    }
}

// ---------- RoPE + RMSNorm for Q and K (reads 2 split-K partials, adds) ----------
// Q scaled by SCALE*log2(e); K written directly in MFMA-fragment order.
__global__ __launch_bounds__(256)
void rope_rms(const bf16* __restrict__ pA, const bf16* __restrict__ pB,
              const float* __restrict__ qg, const float* __restrict__ kg,
              bf16* __restrict__ qo, bf16* __restrict__ kfr) {
  const int gid = blockIdx.x * 4 + (threadIdx.x >> 6);
  const int lane = threadIdx.x & 63;
  const int pos = gid / 40;
  const int hh = gid % 40;            // 0..31 q heads, 32..39 k heads
  const bool isq = hh < 32;
  const int col = isq ? hh * HDIM : NQH * HDIM + (hh - 32) * HDIM;

  const long idx = (long)pos * QKV_N + col + lane;
  float x = (float)pA[idx] + (float)pB[idx];
  float p = __shfl_xor(x, 1);
  const float fi = (float)(lane & ~1) * (1.0f / 64.0f);
  const float inv = powf(50000.0f, -fi);
  const float ang = (float)pos * inv;
  const float sn = sinf(ang), cs = cosf(ang);
  const float r = (lane & 1) ? (p * sn + x * cs) : (x * cs - p * sn);

  float ss = r * r;
#pragma unroll
  for (int off = 1; off < 64; off <<= 1) ss += __shfl_xor(ss, off);
  const float scl = rsqrtf(ss * (1.0f / 64.0f) + 1e-5f);
  const float g = isq ? qg[lane] : kg[lane];
  const float o = r * scl * g;

  if (isq) {
    qo[(long)pos * DMODEL + hh * HDIM + lane] = (bf16)(o * 0.18033688011112042f);
  } else {
    const int kvh = hh - 32;
    const int d = lane;
    const int lp = (pos & 31) + (((d >> 3) & 1) << 5);
    const long kidx = ((((long)kvh * 64 + (pos >> 5)) * 4 + (d >> 4)) * 64 + lp) * 8 + (d & 7);
    kfr[kidx] = (bf16)o;
  }
}

// ---------- V repack (reads 2 split-K partials): -> vfr MFMA-fragment order ----------
__global__ __launch_bounds__(256)
void repack_v(const bf16* __restrict__ pA, const bf16* __restrict__ pB,
              bf16* __restrict__ vfr) {
  __shared__ bf16 t[32][72];
  const int kvh = blockIdx.x >> 6;
  const int kb = blockIdx.x & 63;
  const int tid = threadIdx.x;

  {
    const int row = tid >> 3;
    const int cc = (tid & 7) * 8;
    const long goff = (long)(kb * 32 + row) * QKV_N + (NQH * HDIM + NKVH * HDIM) + kvh * HDIM + cc;
    const bf16x8 a = *reinterpret_cast<const bf16x8*>(pA + goff);
    const bf16x8 b = *reinterpret_cast<const bf16x8*>(pB + goff);
    bf16x8 s;
#pragma unroll
    for (int e = 0; e < 8; ++e) s[e] = (bf16)((float)a[e] + (float)b[e]);
    *reinterpret_cast<bf16x8*>(&t[row][cc]) = s;
  }
  __syncthreads();

  const int f = tid >> 6, l = tid & 63;
  const int s = f >> 1, dh = f & 1;
  const int hi = l >> 5, l31 = l & 31;
  union { bf16 b[8]; u32x4 u; } o;
#pragma unroll
  for (int e = 0; e < 8; ++e) o.b[e] = t[s * 16 + hi * 8 + e][dh * 32 + l31];
  bf16* od = vfr + (((long)(kvh * 64 + kb) * 4 + f) * 64 + l) * 8;
  *reinterpret_cast<u32x4*>(od) = o.u;
}

// ---------- flash attention (causal, GQA), QBLK=64/wave, XCD-pinned ----------
// Each wave owns 64 q-rows (two 32-row MFMA sets A/B of the SAME head) and
// shares ONE set of K/V loads between them: 8 VMEM per 32 keys now serve
// 16 MFMA (2x arithmetic intensity per load vs the 32-row version).
// 640 blocks (kvh = bb&7 XCD pin; 4 waves = 4 q-heads, same (Qb, chunk)),
// biggest chunks first. No LDS, no barriers. r8-style next-K prefetch.
__global__ __launch_bounds__(256, 2)
void flash_attn(const bf16* __restrict__ Q, const bf16* __restrict__ Kfr,
                const bf16* __restrict__ Vfr,
                bf16* __restrict__ po, float* __restrict__ pm, float* __restrict__ pl) {
  const int w = threadIdx.x >> 6, l = threadIdx.x & 63;
  const int lane31 = l & 31, hi = l >> 5;
  const int bb = blockIdx.x;
  const int kvh = bb & 7;               // XCD pin
  const int g = 79 - (bb >> 3);         // 0..79, biggest chunks first

  // invert cumulative chunk id -> (Qb, c)
  int Qb, c;
  if (g < 8)       { Qb = g;                   c = 0; }
  else if (g < 24) { Qb = 8 + ((g - 8) >> 1);  c = (g - 8) & 1; }
  else if (g < 48) { Qb = 16 + (g - 24) / 3;   c = (g - 24) % 3; }
  else             { Qb = 24 + ((g - 48) >> 2); c = (g - 48) & 3; }

  const int h = kvh * 4 + w;            // wave -> q-head
  const int s0 = c * 16;
  const int s1 = min(2 * Qb + 2, s0 + 16);
  const int pidx = h * 80 + g;          // g == chunk_base64(Qb) + c

  const int q0A = Qb * 64;              // first row of set A; set B = +32
  const int qA = q0A + lane31;
  const int qB = q0A + 32 + lane31;
  const int l8 = l * 8;

  const bf16* kfrh = Kfr + (long)kvh * KVF_HSTRIDE;
  const bf16* vfrh = Vfr + (long)kvh * KVF_HSTRIDE;

  // Q fragments for both sets (B-frag of ST): lane -> Q[q][cc*16 + hi*8 + e]
  const bf16* qrowA = Q + (long)qA * DMODEL + h * HDIM + hi * 8;
  const bf16* qrowB = Q + (long)qB * DMODEL + h * HDIM + hi * 8;
  bf16x8 qfA[4], qfB[4];
#pragma unroll
  for (int cc = 0; cc < 4; ++cc) {
    qfA[cc] = *reinterpret_cast<const bf16x8*>(qrowA + cc * 16);
    qfB[cc] = *reinterpret_cast<const bf16x8*>(qrowB + cc * 16);
  }

  f32x16 oA0, oA1, oB0, oB1;
#pragma unroll
  for (int r = 0; r < 16; ++r) { oA0[r] = 0.f; oA1[r] = 0.f; oB0[r] = 0.f; oB1[r] = 0.f; }
  float mA = -3.0e38f, lsA = 0.f, mB = -3.0e38f, lsB = 0.f;

  // prologue: K fragments for subtile s0
  bf16x8 kc0, kc1, kc2, kc3;
  {
    const bf16* kp = kfrh + (long)s0 * 2048 + l8;
    kc0 = *reinterpret_cast<const bf16x8*>(kp);
    kc1 = *reinterpret_cast<const bf16x8*>(kp + 512);
    kc2 = *reinterpret_cast<const bf16x8*>(kp + 1024);
    kc3 = *reinterpret_cast<const bf16x8*>(kp + 1536);
  }

  for (int sti = s0; sti < s1; ++sti) {
    const int kb0 = sti * 32;

    // V loads issued early (consumed after softmax; shared by sets A and B)
    const bf16* vp = vfrh + (long)sti * 2048 + l8;
    const bf16x8 va0 = *reinterpret_cast<const bf16x8*>(vp);
    const bf16x8 vb0 = *reinterpret_cast<const bf16x8*>(vp + 512);
    const bf16x8 va1 = *reinterpret_cast<const bf16x8*>(vp + 1024);
    const bf16x8 vb1 = *reinterpret_cast<const bf16x8*>(vp + 1536);

    // NEXT subtile's K (clamped, branchless — in flight across compute)
    const long knoff = (sti + 1 < s1) ? (long)(sti + 1) * 2048 : (long)s0 * 2048;
    const bf16* kp = kfrh + knoff + l8;
    const bf16x8 kn0 = *reinterpret_cast<const bf16x8*>(kp);
    const bf16x8 kn1 = *reinterpret_cast<const bf16x8*>(kp + 512);
    const bf16x8 kn2 = *reinterpret_cast<const bf16x8*>(kp + 1024);
    const bf16x8 kn3 = *reinterpret_cast<const bf16x8*>(kp + 1536);

    // ================= set A (rows q0A..q0A+31) =================
    if (kb0 <= q0A + 31) {              // skip when fully masked (s == 2Qb+1)
      f32x16 st;
#pragma unroll
      for (int r = 0; r < 16; ++r) st[r] = 0.f;
      st = __builtin_amdgcn_mfma_f32_32x32x16_bf16(kc0, qfA[0], st, 0, 0, 0);
      st = __builtin_amdgcn_mfma_f32_32x32x16_bf16(kc1, qfA[1], st, 0, 0, 0);
      st = __builtin_amdgcn_mfma_f32_32x32x16_bf16(kc2, qfA[2], st, 0, 0, 0);
      st = __builtin_amdgcn_mfma_f32_32x32x16_bf16(kc3, qfA[3], st, 0, 0, 0);

      if (kb0 + 31 > q0A) {             // diagonal subtile for A
#pragma unroll
        for (int r = 0; r < 16; ++r) {
          const int k_abs = kb0 + (r & 3) + 8 * (r >> 2) + 4 * hi;
          if (k_abs > qA) st[r] = -3.0e38f;
        }
      }

      float t[8];
#pragma unroll
      for (int r = 0; r < 8; ++r) t[r] = fmaxf(st[r], st[r + 8]);
#pragma unroll
      for (int s = 4; s > 0; s >>= 1)
#pragma unroll
        for (int r = 0; r < 4; ++r) if (r < s) t[r] = fmaxf(t[r], t[r + s]);
      const float mx = fmaxf(t[0], __shfl_xor(t[0], 32));

      if (!__all(mx - mA <= 8.0f)) {    // defer-max, THR=8
        const float mn = fmaxf(mA, mx);
        const float al = __builtin_amdgcn_exp2f(mA - mn);
        mA = mn; lsA *= al;
#pragma unroll
        for (int r = 0; r < 16; ++r) { oA0[r] *= al; oA1[r] *= al; }
      }
      float rs = 0.f;
#pragma unroll
      for (int r = 0; r < 16; ++r) { st[r] = __builtin_amdgcn_exp2f(st[r] - mA); rs += st[r]; }
      rs += __shfl_xor(rs, 32);
      lsA += rs;

      const bf16x8 pf0 = make_pfrag(st[0], st[1], st[2], st[3], st[4], st[5], st[6], st[7], hi);
      oA0 = __builtin_amdgcn_mfma_f32_32x32x16_bf16(va0, pf0, oA0, 0, 0, 0);
      oA1 = __builtin_amdgcn_mfma_f32_32x32x16_bf16(vb0, pf0, oA1, 0, 0, 0);
      const bf16x8 pf1 = make_pfrag(st[8], st[9], st[10], st[11], st[12], st[13], st[14], st[15], hi);
      oA0 = __builtin_amdgcn_mfma_f32_32x32x16_bf16(va1, pf1, oA0, 0, 0, 0);
      oA1 = __builtin_amdgcn_mfma_f32_32x32x16_bf16(vb1, pf1, oA1, 0, 0, 0);
    }

    // ================= set B (rows q0A+32..q0A+63) =================
    {
      f32x16 st;
#pragma unroll
      for (int r = 0; r < 16; ++r) st[r] = 0.f;
      st = __builtin_amdgcn_mfma_f32_32x32x16_bf16(kc0, qfB[0], st, 0, 0, 0);
      st = __builtin_amdgcn_mfma_f32_32x32x16_bf16(kc1, qfB[1], st, 0, 0, 0);
      st = __builtin_amdgcn_mfma_f32_32x32x16_bf16(kc2, qfB[2], st, 0, 0, 0);
      st = __builtin_amdgcn_mfma_f32_32x32x16_bf16(kc3, qfB[3], st, 0, 0, 0);

      if (kb0 + 31 > q0A + 32) {        // diagonal subtile for B
#pragma unroll
        for (int r = 0; r < 16; ++r) {
          const int k_abs = kb0 + (r & 3) + 8 * (r >> 2) + 4 * hi;
          if (k_abs > qB) st[r] = -3.0e38f;
        }
      }

      float t[8];
#pragma unroll
      for (int r = 0; r < 8; ++r) t[r] = fmaxf(st[r], st[r + 8]);
#pragma unroll
      for (int s = 4; s > 0; s >>= 1)
#pragma unroll
        for (int r = 0; r < 4; ++r) if (r < s) t[r] = fmaxf(t[r], t[r + s]);
      const float mx = fmaxf(t[0], __shfl_xor(t[0], 32));

      if (!__all(mx - mB <= 8.0f)) {
        const float mn = fmaxf(mB, mx);
        const float al = __builtin_amdgcn_exp2f(mB - mn);
        mB = mn; lsB *= al;
#pragma unroll
        for (int r = 0; r < 16; ++r) { oB0[r] *= al; oB1[r] *= al; }
      }
      float rs = 0.f;
#pragma unroll
      for (int r = 0; r < 16; ++r) { st[r] = __builtin_amdgcn_exp2f(st[r] - mB); rs += st[r]; }
      rs += __shfl_xor(rs, 32);
      lsB += rs;

      const bf16x8 pf0 = make_pfrag(st[0], st[1], st[2], st[3], st[4], st[5], st[6], st[7], hi);
      oB0 = __builtin_amdgcn_mfma_f32_32x32x16_bf16(va0, pf0, oB0, 0, 0, 0);
      oB1 = __builtin_amdgcn_mfma_f32_32x32x16_bf16(vb0, pf0, oB1, 0, 0, 0);
      const bf16x8 pf1 = make_pfrag(st[8], st[9], st[10], st[11], st[12], st[13], st[14], st[15], hi);
      oB0 = __builtin_amdgcn_mfma_f32_32x32x16_bf16(va1, pf1, oB0, 0, 0, 0);
      oB1 = __builtin_amdgcn_mfma_f32_32x32x16_bf16(vb1, pf1, oB1, 0, 0, 0);
    }

    kc0 = kn0; kc1 = kn1; kc2 = kn2; kc3 = kn3;
  }

  // ---- store bf16 partial (64 rows x 64 d, unnormalized) + f32 stats ----
  bf16* pbase = po + (long)pidx * 4096;
#pragma unroll
  for (int gg = 0; gg < 4; ++gg) {
    const int d0 = 8 * gg + 4 * hi;
    u32x2 a0 = { pack2(oA0[4 * gg + 0], oA0[4 * gg + 1]),
                 pack2(oA0[4 * gg + 2], oA0[4 * gg + 3]) };
    u32x2 a1 = { pack2(oA1[4 * gg + 0], oA1[4 * gg + 1]),
                 pack2(oA1[4 * gg + 2], oA1[4 * gg + 3]) };
    *reinterpret_cast<u32x2*>(pbase + lane31 * 64 + d0) = a0;
    *reinterpret_cast<u32x2*>(pbase + lane31 * 64 + 32 + d0) = a1;
    u32x2 b0 = { pack2(oB0[4 * gg + 0], oB0[4 * gg + 1]),
                 pack2(oB0[4 * gg + 2], oB0[4 * gg + 3]) };
    u32x2 b1 = { pack2(oB1[4 * gg + 0], oB1[4 * gg + 1]),
                 pack2(oB1[4 * gg + 2], oB1[4 * gg + 3]) };
    *reinterpret_cast<u32x2*>(pbase + (32 + lane31) * 64 + d0) = b0;
    *reinterpret_cast<u32x2*>(pbase + (32 + lane31) * 64 + 32 + d0) = b1;
  }
  if (hi == 0) {
    pm[pidx * 64 + lane31] = mA;
    pl[pidx * 64 + lane31] = lsA;
    pm[pidx * 64 + 32 + lane31] = mB;
    pl[pidx * 64 + 32 + lane31] = lsB;
  }
}

// ---------- combine partials: ao[q] = Σ_c O_c·2^(m_c−M) / Σ_c l_c·2^(m_c−M) ----------
// 1024 tiles (h, Qb) of 64 rows; nc = ceil((2Qb+2)/16) partials (1..4).
__global__ __launch_bounds__(256)
void combine_split(const bf16* __restrict__ po, const float* __restrict__ pm,
                   const float* __restrict__ pl, bf16* __restrict__ ao) {
  const int t = blockIdx.x;
  const int tid = threadIdx.x;
  const int r = tid >> 2;                  // q row 0..63
  const int dc = (tid & 3) * 16;           // d chunk
  const int h = t >> 5, Qb = t & 31;
  const int nc = (Qb < 8) ? 1 : (Qb < 16) ? 2 : (Qb < 24) ? 3 : 4;
  const int p0 = h * 80 + chunk_base64(Qb);

  float mv0 = -3e38f, mv1 = -3e38f, mv2 = -3e38f, mv3 = -3e38f;
  float lv0 = 0.f, lv1 = 0.f, lv2 = 0.f, lv3 = 0.f;
  mv0 = pm[(p0 + 0) * 64 + r];              lv0 = pl[(p0 + 0) * 64 + r];
  if (nc > 1) { mv1 = pm[(p0 + 1) * 64 + r]; lv1 = pl[(p0 + 1) * 64 + r]; }
  if (nc > 2) { mv2 = pm[(p0 + 2) * 64 + r]; lv2 = pl[(p0 + 2) * 64 + r]; }
  if (nc > 3) { mv3 = pm[(p0 + 3) * 64 + r]; lv3 = pl[(p0 + 3) * 64 + r]; }
  const float M = fmaxf(fmaxf(mv0, mv1), fmaxf(mv2, mv3));
  const float w0 = __builtin_amdgcn_exp2f(mv0 - M);
  const float w1 = (nc > 1) ? __builtin_amdgcn_exp2f(mv1 - M) : 0.f;
  const float w2 = (nc > 2) ? __builtin_amdgcn_exp2f(mv2 - M) : 0.f;
  const float w3 = (nc > 3) ? __builtin_amdgcn_exp2f(mv3 - M) : 0.f;
  const float invL = 1.0f / (lv0 * w0 + lv1 * w1 + lv2 * w2 + lv3 * w3);

  float acc[16];
#pragma unroll
  for (int j = 0; j < 16; ++j) acc[j] = 0.f;

#pragma unroll
  for (int c = 0; c < 4; ++c) {
    if (c < nc) {
      const float fc = ((c == 0) ? w0 : (c == 1) ? w1 : (c == 2) ? w2 : w3) * invL;
      const bf16* src = po + ((long)(p0 + c) * 4096) + r * 64 + dc;
      const bf16x8 a0 = *reinterpret_cast<const bf16x8*>(src);
      const bf16x8 a1 = *reinterpret_cast<const bf16x8*>(src + 8);
#pragma unroll
      for (int j = 0; j < 8; ++j) {
        acc[j]     += (float)a0[j] * fc;
        acc[8 + j] += (float)a1[j] * fc;
      }
    }
  }

  const long q_abs = (long)Qb * 64 + r;
  bf16* od = ao + q_abs * DMODEL + h * HDIM + dc;
  union { bf16 b[16]; u32x4 u[2]; } o;
#pragma unroll
  for (int j = 0; j < 16; ++j) o.b[j] = (bf16)acc[j];
  *reinterpret_cast<u32x4*>(od) = o.u[0];
  *reinterpret_cast<u32x4*>(od + 8) = o.u[1];
}

// ---------- launch ----------
extern "C" void kernel_launch(void* const* d_in, const int* in_sizes, int n_in,
                              void* d_out, int out_size, void* d_ws, size_t ws_size,
                              hipStream_t stream) {
  const float* x       = (const float*)d_in[0];
  const float* w_qkv   = (const float*)d_in[1];
  const float* w_out   = (const float*)d_in[2];
  const float* q_gamma = (const float*)d_in[3];
  const float* k_gamma = (const float*)d_in[4];
  // d_in[5] = mask (causal tril) — implemented analytically.

  char* ws = (char*)d_ws;
  // Region lifetimes (MB offsets):
  bf16* xb    = (bf16*)(ws);                     //  0..8   x bf16 (dead after gemm1)
  bf16* wqb   = (bf16*)(ws + (8ul  << 20));      //  8..20  w_qkv bf16 (dead after gemm1)
  bf16* wob   = (bf16*)(ws + (20ul << 20));      // 20..28  w_out bf16 (until gemm2)
  bf16* qkvpA = (bf16*)(ws + (28ul << 20));      // 28..40  qkv split-K partial 0
  bf16* qkvpB = (bf16*)(ws + (40ul << 20));      // 40..52  qkv split-K partial 1 (dead after rope/repack)
  bf16* qb    = (bf16*)(ws);                     //  0..8   Q (over dead xb)
  bf16* kfr   = (bf16*)(ws + (8ul  << 20));      //  8..10  K frag order (over dead wqb)
  bf16* vfr   = (bf16*)(ws + (10ul << 20));      // 10..12  V frag order
  bf16* po    = (bf16*)(ws + (28ul << 20));      // 28..48  attn partials (2560 x 8KB, over dead qkvp)
  float* pm   = (float*)(ws + (48ul << 20));     // 48..48.7
  float* pl   = (float*)(ws + (49ul << 20));     // 49..49.7
  bf16* ao    = (bf16*)(ws + (52ul << 20));      // 52..60  attention out
  float* out  = (float*)d_out;

  cvt3_f32_bf16<<<2048, 256, 0, stream>>>(x, w_qkv, w_out, xb, wqb, wob);

  // QKV GEMM split-K=2: 768x2 blocks
  gemm_bt<bf16><<<dim3(QKV_N / 64, L_SEQ / 128, 2), 128, 0, stream>>>(xb, wqb, qkvpA, L_SEQ, QKV_N, DMODEL);

  rope_rms<<<(L_SEQ * 40) / 4, 256, 0, stream>>>(qkvpA, qkvpB, q_gamma, k_gamma, qb, kfr);
  repack_v<<<NKVH * (L_SEQ / 32), 256, 0, stream>>>(qkvpA, qkvpB, vfr);

  flash_attn<<<640, 256, 0, stream>>>(qb, kfr, vfr, po, pm, pl);
  combine_split<<<1024, 256, 0, stream>>>(po, pm, pl, ao);

  gemm_bt<float><<<dim3(DMODEL / 64, L_SEQ / 128, 1), 128, 0, stream>>>(ao, wob, out, L_SEQ, DMODEL, DMODEL);
}

// Round 14
// 162.016 us; speedup vs baseline: 1.0594x; 1.0594x over previous
//
#include <hip/hip_runtime.h>

using bf16   = __bf16;
using bf16x4 = __bf16 __attribute__((ext_vector_type(4)));
using bf16x8 = __bf16 __attribute__((ext_vector_type(8)));
using f32x4  = float __attribute__((ext_vector_type(4)));
using f32x16 = float __attribute__((ext_vector_type(16)));
using u32x2  = unsigned int __attribute__((ext_vector_type(2)));
using u32x4  = unsigned int __attribute__((ext_vector_type(4)));

#define L_SEQ  2048
#define DMODEL 2048
#define NQH    32
#define NKVH   8
#define HDIM   64
#define QKV_N  3072   // NQH*HDIM + 2*NKVH*HDIM

// fragment-ordered K/V: per kv-head, 64 key-blocks of 32; each block = 4 frags
// of (64 lanes x 8 elems) = 2048 elems; per-head stride:
#define KVF_HSTRIDE (64 * 4 * 64 * 8)   // 131072 elems = 256 KiB

// Fixed softmax shift: |st| <= 64*max(g_q)*max(g_k)*SCALE*log2e ~= 13 (RMSNorm
// bounds ||q||,||k|| <= 8*max|gamma| for ANY input; gamma ~ 1+-0.06). M=16 gives
// headroom; softmax is shift-invariant so the result is exact, and bf16/f32
// relative precision is scale-free.
#define FIXED_M 16.0f

// ---------- helpers ----------
__device__ __forceinline__ void gload_lds16(const void* g, void* lds) {
  __builtin_amdgcn_global_load_lds((__attribute__((address_space(1))) void*)(g),
                                   (__attribute__((address_space(3))) void*)(lds),
                                   16, 0, 0);
}

__device__ __forceinline__ unsigned pack2(float a, float b) {
  union { bf16 h[2]; unsigned u; } x;
  x.h[0] = (bf16)a; x.h[1] = (bf16)b;
  return x.u;
}

// assemble the PV B-fragment from 8 per-lane P values (swapped layout)
__device__ __forceinline__ bf16x8 make_pfrag(float p0, float p1, float p2, float p3,
                                             float p4, float p5, float p6, float p7,
                                             int hi) {
  const unsigned W0 = pack2(p0, p1);
  const unsigned W1 = pack2(p2, p3);
  const unsigned W2 = pack2(p4, p5);
  const unsigned W3 = pack2(p6, p7);
  u32x4 pw;
#if __has_builtin(__builtin_amdgcn_permlane32_swap)
  {
    using i32x2 = int __attribute__((ext_vector_type(2)));
    const i32x2 r02 = __builtin_amdgcn_permlane32_swap((int)W0, (int)W2, false, false);
    const i32x2 r13 = __builtin_amdgcn_permlane32_swap((int)W1, (int)W3, false, false);
    pw = u32x4{ (unsigned)r02[0], (unsigned)r13[0], (unsigned)r02[1], (unsigned)r13[1] };
  }
#else
  {
    const unsigned X0 = (unsigned)__shfl_xor((int)W0, 32);
    const unsigned X1 = (unsigned)__shfl_xor((int)W1, 32);
    const unsigned X2 = (unsigned)__shfl_xor((int)W2, 32);
    const unsigned X3 = (unsigned)__shfl_xor((int)W3, 32);
    pw = u32x4{ hi ? X2 : W0, hi ? X3 : W1, hi ? W2 : X0, hi ? W3 : X1 };
  }
#endif
  return __builtin_bit_cast(bf16x8, pw);
}

// cumulative chunk count before q-superblock Qb (64 q-rows each; chunks of 16
// key-subtiles; Qb needs 2*Qb+2 subtiles)
__device__ __forceinline__ int chunk_base64(int Qb) {
  return (Qb < 8)  ? Qb
       : (Qb < 16) ? 8  + 2 * (Qb - 8)
       : (Qb < 24) ? 24 + 3 * (Qb - 16)
                   : 48 + 4 * (Qb - 24);
}

// ---------- fused fp32 -> bf16 convert (x, w_qkv, w_out in one launch) ----------
#define N4_X  (L_SEQ * DMODEL / 4)          // 1048576
#define N4_WQ (QKV_N * DMODEL / 4)          // 1572864
#define N4_WO (DMODEL * DMODEL / 4)         // 1048576
__global__ void cvt3_f32_bf16(const float* __restrict__ x, const float* __restrict__ wq,
                              const float* __restrict__ wo, bf16* __restrict__ xb,
                              bf16* __restrict__ wqb, bf16* __restrict__ wob) {
  const long stride = (long)gridDim.x * blockDim.x;
  const long ntot = N4_X + N4_WQ + N4_WO;
  for (long i = (long)blockIdx.x * blockDim.x + threadIdx.x; i < ntot; i += stride) {
    const float* src; bf16* dst; long j;
    if (i < N4_X)               { src = x;  dst = xb;  j = i; }
    else if (i < N4_X + N4_WQ)  { src = wq; dst = wqb; j = i - N4_X; }
    else                        { src = wo; dst = wob; j = i - N4_X - N4_WQ; }
    const float4 v = reinterpret_cast<const float4*>(src)[j];
    bf16x4 o = { (bf16)v.x, (bf16)v.y, (bf16)v.z, (bf16)v.w };
    reinterpret_cast<bf16x4*>(dst)[j] = o;
  }
}

// ---------- bf16 GEMM: C(MxN) = A(MxK) * B(NxK)^T, 128x64 tile, BK=64 ----------
// 2 waves per block; each wave computes the FULL 64x64 half-tile.
// Split-K via gridDim.z: block z covers K-range [z*K/gz, (z+1)*K/gz), writing
// its partial to C + z*M*N. gz=1 -> plain GEMM.
template <typename OutT>
__global__ __launch_bounds__(128)
void gemm_bt(const bf16* __restrict__ A, const bf16* __restrict__ B,
             OutT* __restrict__ C, int M, int N, int K) {
  __shared__ bf16 As[128 * 64];
  __shared__ bf16 Bs[64 * 64];
  const int tid = threadIdx.x;
  const int w = tid >> 6, l = tid & 63;
  const int lq = l & 15, lg = l >> 4;
  const long m0 = (long)blockIdx.y * 128;
  const long n0 = (long)blockIdx.x * 64;
  const int ks = K / gridDim.z;
  const int kb = blockIdx.z * ks;
  C += (long)blockIdx.z * M * N;

  const int lrow = l >> 3;                   // row within 8-row group (0..7)
  const int scol = ((l & 7) ^ lrow) << 3;    // pre-swizzled global element column

  f32x4 acc[4][4];
#pragma unroll
  for (int i = 0; i < 4; ++i)
#pragma unroll
    for (int j = 0; j < 4; ++j) acc[i][j] = f32x4{0.f, 0.f, 0.f, 0.f};

  for (int k0 = kb; k0 < kb + ks; k0 += 64) {
#pragma unroll
    for (int i = 0; i < 8; ++i) {
      const int r0 = (i * 2 + w) * 8;
      gload_lds16(A + (m0 + r0 + lrow) * (long)K + k0 + scol, &As[r0 * 64]);
    }
#pragma unroll
    for (int i = 0; i < 4; ++i) {
      const int r0 = (i * 2 + w) * 8;
      gload_lds16(B + (n0 + r0 + lrow) * (long)K + k0 + scol, &Bs[r0 * 64]);
    }
    __syncthreads();
#pragma unroll
    for (int kk = 0; kk < 2; ++kk) {
      bf16x8 af[4], bfr[4];
#pragma unroll
      for (int t = 0; t < 4; ++t) {
        const int rowA = w * 64 + t * 16 + lq;
        const int blkA = (kk * 4 + lg) ^ (rowA & 7);
        af[t] = *reinterpret_cast<const bf16x8*>(&As[rowA * 64 + blkA * 8]);
        const int rowB = t * 16 + lq;
        const int blkB = (kk * 4 + lg) ^ (rowB & 7);
        bfr[t] = *reinterpret_cast<const bf16x8*>(&Bs[rowB * 64 + blkB * 8]);
      }
#pragma unroll
      for (int mt = 0; mt < 4; ++mt)
#pragma unroll
        for (int nt = 0; nt < 4; ++nt)
          acc[mt][nt] = __builtin_amdgcn_mfma_f32_16x16x32_bf16(af[mt], bfr[nt], acc[mt][nt], 0, 0, 0);
    }
    __syncthreads();
  }

#pragma unroll
  for (int mt = 0; mt < 4; ++mt)
#pragma unroll
    for (int r = 0; r < 4; ++r) {
      const long row = m0 + w * 64 + mt * 16 + lg * 4 + r;
#pragma unroll
      for (int nt = 0; nt < 4; ++nt) {
        const long col = n0 + nt * 16 + lq;
        C[row * (long)N + col] = (OutT)acc[mt][nt][r];
      }
    }
}

// ---------- fused RoPE+RMSNorm (q,k) AND V repack, one launch ----------
// blocks [0, 20480): rope path; [20480, 20992): V repack path.
__global__ __launch_bounds__(256)
void rope_repack(const bf16* __restrict__ pA, const bf16* __restrict__ pB,
                 const float* __restrict__ qg, const float* __restrict__ kg,
                 bf16* __restrict__ qo, bf16* __restrict__ kfr, bf16* __restrict__ vfr) {
  __shared__ bf16 t[32][72];
  if (blockIdx.x < 20480) {
    // ---- RoPE + RMSNorm; Q scaled by SCALE*log2(e); K -> frag order ----
    const int gid = blockIdx.x * 4 + (threadIdx.x >> 6);
    const int lane = threadIdx.x & 63;
    const int pos = gid / 40;
    const int hh = gid % 40;          // 0..31 q heads, 32..39 k heads
    const bool isq = hh < 32;
    const int col = isq ? hh * HDIM : NQH * HDIM + (hh - 32) * HDIM;

    const long idx = (long)pos * QKV_N + col + lane;
    float x = (float)pA[idx] + (float)pB[idx];
    float p = __shfl_xor(x, 1);
    const float fi = (float)(lane & ~1) * (1.0f / 64.0f);
    const float inv = powf(50000.0f, -fi);
    const float ang = (float)pos * inv;
    const float sn = sinf(ang), cs = cosf(ang);
    const float r = (lane & 1) ? (p * sn + x * cs) : (x * cs - p * sn);

    float ss = r * r;
#pragma unroll
    for (int off = 1; off < 64; off <<= 1) ss += __shfl_xor(ss, off);
    const float scl = rsqrtf(ss * (1.0f / 64.0f) + 1e-5f);
    const float g = isq ? qg[lane] : kg[lane];
    const float o = r * scl * g;

    if (isq) {
      qo[(long)pos * DMODEL + hh * HDIM + lane] = (bf16)(o * 0.18033688011112042f);
    } else {
      const int kvh = hh - 32;
      const int d = lane;
      const int lp = (pos & 31) + (((d >> 3) & 1) << 5);
      const long kidx = ((((long)kvh * 64 + (pos >> 5)) * 4 + (d >> 4)) * 64 + lp) * 8 + (d & 7);
      kfr[kidx] = (bf16)o;
    }
  } else {
    // ---- V repack -> MFMA-fragment order ----
    const int bid = blockIdx.x - 20480;
    const int kvh = bid >> 6;
    const int kb = bid & 63;
    const int tid = threadIdx.x;
    {
      const int row = tid >> 3;
      const int cc = (tid & 7) * 8;
      const long goff = (long)(kb * 32 + row) * QKV_N + (NQH * HDIM + NKVH * HDIM) + kvh * HDIM + cc;
      const bf16x8 a = *reinterpret_cast<const bf16x8*>(pA + goff);
      const bf16x8 b = *reinterpret_cast<const bf16x8*>(pB + goff);
      bf16x8 s;
#pragma unroll
      for (int e = 0; e < 8; ++e) s[e] = (bf16)((float)a[e] + (float)b[e]);
      *reinterpret_cast<bf16x8*>(&t[row][cc]) = s;
    }
    __syncthreads();

    const int f = tid >> 6, l = tid & 63;
    const int s = f >> 1, dh = f & 1;
    const int hi = l >> 5, l31 = l & 31;
    union { bf16 b[8]; u32x4 u; } o;
#pragma unroll
    for (int e = 0; e < 8; ++e) o.b[e] = t[s * 16 + hi * 8 + e][dh * 32 + l31];
    bf16* od = vfr + (((long)(kvh * 64 + kb) * 4 + f) * 64 + l) * 8;
    *reinterpret_cast<u32x4*>(od) = o.u;
  }
}

// ---------- flash attention (causal, GQA), QBLK=64/wave, fixed-max softmax ----------
// No online-max tracking: P = exp2(st - 16) (logits bounded by RMSNorm; exact
// by shift-invariance). Single-chunk units (g < 8) normalize and write ao
// directly; others store bf16 partials + lsum. XCD-pinned, biggest first.
__global__ __launch_bounds__(256, 2)
void flash_attn(const bf16* __restrict__ Q, const bf16* __restrict__ Kfr,
                const bf16* __restrict__ Vfr,
                bf16* __restrict__ po, float* __restrict__ pl, bf16* __restrict__ ao) {
  const int w = threadIdx.x >> 6, l = threadIdx.x & 63;
  const int lane31 = l & 31, hi = l >> 5;
  const int bb = blockIdx.x;
  const int kvh = bb & 7;               // XCD pin
  const int g = 79 - (bb >> 3);         // 0..79, biggest chunks first

  // invert cumulative chunk id -> (Qb, c)
  int Qb, c;
  if (g < 8)       { Qb = g;                   c = 0; }
  else if (g < 24) { Qb = 8 + ((g - 8) >> 1);  c = (g - 8) & 1; }
  else if (g < 48) { Qb = 16 + (g - 24) / 3;   c = (g - 24) % 3; }
  else             { Qb = 24 + ((g - 48) >> 2); c = (g - 48) & 3; }

  const int h = kvh * 4 + w;            // wave -> q-head
  const int s0 = c * 16;
  const int s1 = min(2 * Qb + 2, s0 + 16);
  const int pidx = h * 80 + g;          // g == chunk_base64(Qb) + c

  const int q0A = Qb * 64;              // first row of set A; set B = +32
  const int qA = q0A + lane31;
  const int qB = q0A + 32 + lane31;
  const int l8 = l * 8;

  const bf16* kfrh = Kfr + (long)kvh * KVF_HSTRIDE;
  const bf16* vfrh = Vfr + (long)kvh * KVF_HSTRIDE;

  // Q fragments for both sets (B-frag of ST): lane -> Q[q][cc*16 + hi*8 + e]
  const bf16* qrowA = Q + (long)qA * DMODEL + h * HDIM + hi * 8;
  const bf16* qrowB = Q + (long)qB * DMODEL + h * HDIM + hi * 8;
  bf16x8 qfA[4], qfB[4];
#pragma unroll
  for (int cc = 0; cc < 4; ++cc) {
    qfA[cc] = *reinterpret_cast<const bf16x8*>(qrowA + cc * 16);
    qfB[cc] = *reinterpret_cast<const bf16x8*>(qrowB + cc * 16);
  }

  f32x16 oA0, oA1, oB0, oB1;
#pragma unroll
  for (int r = 0; r < 16; ++r) { oA0[r] = 0.f; oA1[r] = 0.f; oB0[r] = 0.f; oB1[r] = 0.f; }
  float lsA = 0.f, lsB = 0.f;

  // prologue: K fragments for subtile s0
  bf16x8 kc0, kc1, kc2, kc3;
  {
    const bf16* kp = kfrh + (long)s0 * 2048 + l8;
    kc0 = *reinterpret_cast<const bf16x8*>(kp);
    kc1 = *reinterpret_cast<const bf16x8*>(kp + 512);
    kc2 = *reinterpret_cast<const bf16x8*>(kp + 1024);
    kc3 = *reinterpret_cast<const bf16x8*>(kp + 1536);
  }

  for (int sti = s0; sti < s1; ++sti) {
    const int kb0 = sti * 32;

    // V loads issued early (shared by sets A and B)
    const bf16* vp = vfrh + (long)sti * 2048 + l8;
    const bf16x8 va0 = *reinterpret_cast<const bf16x8*>(vp);
    const bf16x8 vb0 = *reinterpret_cast<const bf16x8*>(vp + 512);
    const bf16x8 va1 = *reinterpret_cast<const bf16x8*>(vp + 1024);
    const bf16x8 vb1 = *reinterpret_cast<const bf16x8*>(vp + 1536);

    // NEXT subtile's K (clamped, branchless — in flight across compute)
    const long knoff = (sti + 1 < s1) ? (long)(sti + 1) * 2048 : (long)s0 * 2048;
    const bf16* kp = kfrh + knoff + l8;
    const bf16x8 kn0 = *reinterpret_cast<const bf16x8*>(kp);
    const bf16x8 kn1 = *reinterpret_cast<const bf16x8*>(kp + 512);
    const bf16x8 kn2 = *reinterpret_cast<const bf16x8*>(kp + 1024);
    const bf16x8 kn3 = *reinterpret_cast<const bf16x8*>(kp + 1536);

    // ================= set A (rows q0A..q0A+31) =================
    if (kb0 <= q0A + 31) {              // skip when fully masked
      f32x16 st;
#pragma unroll
      for (int r = 0; r < 16; ++r) st[r] = 0.f;
      st = __builtin_amdgcn_mfma_f32_32x32x16_bf16(kc0, qfA[0], st, 0, 0, 0);
      st = __builtin_amdgcn_mfma_f32_32x32x16_bf16(kc1, qfA[1], st, 0, 0, 0);
      st = __builtin_amdgcn_mfma_f32_32x32x16_bf16(kc2, qfA[2], st, 0, 0, 0);
      st = __builtin_amdgcn_mfma_f32_32x32x16_bf16(kc3, qfA[3], st, 0, 0, 0);

      if (kb0 + 31 > q0A) {             // diagonal subtile for A
#pragma unroll
        for (int r = 0; r < 16; ++r) {
          const int k_abs = kb0 + (r & 3) + 8 * (r >> 2) + 4 * hi;
          if (k_abs > qA) st[r] = -3.0e38f;
        }
      }

      float rs = 0.f;
#pragma unroll
      for (int r = 0; r < 16; ++r) { st[r] = __builtin_amdgcn_exp2f(st[r] - FIXED_M); rs += st[r]; }
      rs += __shfl_xor(rs, 32);
      lsA += rs;

      const bf16x8 pf0 = make_pfrag(st[0], st[1], st[2], st[3], st[4], st[5], st[6], st[7], hi);
      oA0 = __builtin_amdgcn_mfma_f32_32x32x16_bf16(va0, pf0, oA0, 0, 0, 0);
      oA1 = __builtin_amdgcn_mfma_f32_32x32x16_bf16(vb0, pf0, oA1, 0, 0, 0);
      const bf16x8 pf1 = make_pfrag(st[8], st[9], st[10], st[11], st[12], st[13], st[14], st[15], hi);
      oA0 = __builtin_amdgcn_mfma_f32_32x32x16_bf16(va1, pf1, oA0, 0, 0, 0);
      oA1 = __builtin_amdgcn_mfma_f32_32x32x16_bf16(vb1, pf1, oA1, 0, 0, 0);
    }

    // ================= set B (rows q0A+32..q0A+63) =================
    {
      f32x16 st;
#pragma unroll
      for (int r = 0; r < 16; ++r) st[r] = 0.f;
      st = __builtin_amdgcn_mfma_f32_32x32x16_bf16(kc0, qfB[0], st, 0, 0, 0);
      st = __builtin_amdgcn_mfma_f32_32x32x16_bf16(kc1, qfB[1], st, 0, 0, 0);
      st = __builtin_amdgcn_mfma_f32_32x32x16_bf16(kc2, qfB[2], st, 0, 0, 0);
      st = __builtin_amdgcn_mfma_f32_32x32x16_bf16(kc3, qfB[3], st, 0, 0, 0);

      if (kb0 + 31 > q0A + 32) {        // diagonal subtile for B
#pragma unroll
        for (int r = 0; r < 16; ++r) {
          const int k_abs = kb0 + (r & 3) + 8 * (r >> 2) + 4 * hi;
          if (k_abs > qB) st[r] = -3.0e38f;
        }
      }

      float rs = 0.f;
#pragma unroll
      for (int r = 0; r < 16; ++r) { st[r] = __builtin_amdgcn_exp2f(st[r] - FIXED_M); rs += st[r]; }
      rs += __shfl_xor(rs, 32);
      lsB += rs;

      const bf16x8 pf0 = make_pfrag(st[0], st[1], st[2], st[3], st[4], st[5], st[6], st[7], hi);
      oB0 = __builtin_amdgcn_mfma_f32_32x32x16_bf16(va0, pf0, oB0, 0, 0, 0);
      oB1 = __builtin_amdgcn_mfma_f32_32x32x16_bf16(vb0, pf0, oB1, 0, 0, 0);
      const bf16x8 pf1 = make_pfrag(st[8], st[9], st[10], st[11], st[12], st[13], st[14], st[15], hi);
      oB0 = __builtin_amdgcn_mfma_f32_32x32x16_bf16(va1, pf1, oB0, 0, 0, 0);
      oB1 = __builtin_amdgcn_mfma_f32_32x32x16_bf16(vb1, pf1, oB1, 0, 0, 0);
    }

    kc0 = kn0; kc1 = kn1; kc2 = kn2; kc3 = kn3;
  }

  if (g < 8) {
    // ---- single-chunk unit: normalize and write ao directly ----
    const float rlA = 1.0f / lsA, rlB = 1.0f / lsB;
    bf16* orowA = ao + (long)qA * DMODEL + h * HDIM;
    bf16* orowB = ao + (long)qB * DMODEL + h * HDIM;
#pragma unroll
    for (int gg = 0; gg < 4; ++gg) {
      const int d0 = 8 * gg + 4 * hi;
      u32x2 a0 = { pack2(oA0[4 * gg + 0] * rlA, oA0[4 * gg + 1] * rlA),
                   pack2(oA0[4 * gg + 2] * rlA, oA0[4 * gg + 3] * rlA) };
      u32x2 a1 = { pack2(oA1[4 * gg + 0] * rlA, oA1[4 * gg + 1] * rlA),
                   pack2(oA1[4 * gg + 2] * rlA, oA1[4 * gg + 3] * rlA) };
      *reinterpret_cast<u32x2*>(orowA + d0) = a0;
      *reinterpret_cast<u32x2*>(orowA + 32 + d0) = a1;
      u32x2 b0 = { pack2(oB0[4 * gg + 0] * rlB, oB0[4 * gg + 1] * rlB),
                   pack2(oB0[4 * gg + 2] * rlB, oB0[4 * gg + 3] * rlB) };
      u32x2 b1 = { pack2(oB1[4 * gg + 0] * rlB, oB1[4 * gg + 1] * rlB),
                   pack2(oB1[4 * gg + 2] * rlB, oB1[4 * gg + 3] * rlB) };
      *reinterpret_cast<u32x2*>(orowB + d0) = b0;
      *reinterpret_cast<u32x2*>(orowB + 32 + d0) = b1;
    }
  } else {
    // ---- store bf16 partial (64 rows x 64 d, unnormalized) + lsum ----
    bf16* pbase = po + (long)pidx * 4096;
#pragma unroll
    for (int gg = 0; gg < 4; ++gg) {
      const int d0 = 8 * gg + 4 * hi;
      u32x2 a0 = { pack2(oA0[4 * gg + 0], oA0[4 * gg + 1]),
                   pack2(oA0[4 * gg + 2], oA0[4 * gg + 3]) };
      u32x2 a1 = { pack2(oA1[4 * gg + 0], oA1[4 * gg + 1]),
                   pack2(oA1[4 * gg + 2], oA1[4 * gg + 3]) };
      *reinterpret_cast<u32x2*>(pbase + lane31 * 64 + d0) = a0;
      *reinterpret_cast<u32x2*>(pbase + lane31 * 64 + 32 + d0) = a1;
      u32x2 b0 = { pack2(oB0[4 * gg + 0], oB0[4 * gg + 1]),
                   pack2(oB0[4 * gg + 2], oB0[4 * gg + 3]) };
      u32x2 b1 = { pack2(oB1[4 * gg + 0], oB1[4 * gg + 1]),
                   pack2(oB1[4 * gg + 2], oB1[4 * gg + 3]) };
      *reinterpret_cast<u32x2*>(pbase + (32 + lane31) * 64 + d0) = b0;
      *reinterpret_cast<u32x2*>(pbase + (32 + lane31) * 64 + 32 + d0) = b1;
    }
    if (hi == 0) {
      pl[pidx * 64 + lane31] = lsA;
      pl[pidx * 64 + 32 + lane31] = lsB;
    }
  }
}

// ---------- combine partials: ao[q] = Σ_c O_c / Σ_c l_c (fixed max -> weights 1) ----------
// 768 tiles: (h, Qb in [8,32)) of 64 rows; nc = ceil((2Qb+2)/16) in {2,3,4}.
__global__ __launch_bounds__(256)
void combine_split(const bf16* __restrict__ po, const float* __restrict__ pl,
                   bf16* __restrict__ ao) {
  const int t = blockIdx.x;
  const int tid = threadIdx.x;
  const int r = tid >> 2;                  // q row 0..63
  const int dc = (tid & 3) * 16;           // d chunk
  const int h = t / 24;
  const int Qb = 8 + (t % 24);
  const int nc = (Qb < 16) ? 2 : (Qb < 24) ? 3 : 4;
  const int p0 = h * 80 + chunk_base64(Qb);

  float lv = pl[(p0 + 0) * 64 + r] + pl[(p0 + 1) * 64 + r];
  if (nc > 2) lv += pl[(p0 + 2) * 64 + r];
  if (nc > 3) lv += pl[(p0 + 3) * 64 + r];
  const float invL = 1.0f / lv;

  float acc[16];
#pragma unroll
  for (int j = 0; j < 16; ++j) acc[j] = 0.f;

#pragma unroll
  for (int c = 0; c < 4; ++c) {
    if (c < nc) {
      const bf16* src = po + ((long)(p0 + c) * 4096) + r * 64 + dc;
      const bf16x8 a0 = *reinterpret_cast<const bf16x8*>(src);
      const bf16x8 a1 = *reinterpret_cast<const bf16x8*>(src + 8);
#pragma unroll
      for (int j = 0; j < 8; ++j) {
        acc[j]     += (float)a0[j];
        acc[8 + j] += (float)a1[j];
      }
    }
  }

  const long q_abs = (long)Qb * 64 + r;
  bf16* od = ao + q_abs * DMODEL + h * HDIM + dc;
  union { bf16 b[16]; u32x4 u[2]; } o;
#pragma unroll
  for (int j = 0; j < 16; ++j) o.b[j] = (bf16)(acc[j] * invL);
  *reinterpret_cast<u32x4*>(od) = o.u[0];
  *reinterpret_cast<u32x4*>(od + 8) = o.u[1];
}

// ---------- launch ----------
extern "C" void kernel_launch(void* const* d_in, const int* in_sizes, int n_in,
                              void* d_out, int out_size, void* d_ws, size_t ws_size,
                              hipStream_t stream) {
  const float* x       = (const float*)d_in[0];
  const float* w_qkv   = (const float*)d_in[1];
  const float* w_out   = (const float*)d_in[2];
  const float* q_gamma = (const float*)d_in[3];
  const float* k_gamma = (const float*)d_in[4];
  // d_in[5] = mask (causal tril) — implemented analytically.

  char* ws = (char*)d_ws;
  // Region lifetimes (MB offsets):
  bf16* xb    = (bf16*)(ws);                     //  0..8   x bf16 (dead after gemm1)
  bf16* wqb   = (bf16*)(ws + (8ul  << 20));      //  8..20  w_qkv bf16 (dead after gemm1)
  bf16* wob   = (bf16*)(ws + (20ul << 20));      // 20..28  w_out bf16 (until gemm2)
  bf16* qkvpA = (bf16*)(ws + (28ul << 20));      // 28..40  qkv split-K partial 0
  bf16* qkvpB = (bf16*)(ws + (40ul << 20));      // 40..52  qkv split-K partial 1 (dead after rope_repack)
  bf16* qb    = (bf16*)(ws);                     //  0..8   Q (over dead xb)
  bf16* kfr   = (bf16*)(ws + (8ul  << 20));      //  8..10  K frag order (over dead wqb)
  bf16* vfr   = (bf16*)(ws + (10ul << 20));      // 10..12  V frag order
  bf16* po    = (bf16*)(ws + (28ul << 20));      // 28..48  attn partials (2560 x 8KB, over dead qkvp)
  float* pl   = (float*)(ws + (48ul << 20));     // 48..48.7
  bf16* ao    = (bf16*)(ws + (52ul << 20));      // 52..60  attention out
  float* out  = (float*)d_out;

  cvt3_f32_bf16<<<2048, 256, 0, stream>>>(x, w_qkv, w_out, xb, wqb, wob);

  // QKV GEMM split-K=2: 768x2 blocks
  gemm_bt<bf16><<<dim3(QKV_N / 64, L_SEQ / 128, 2), 128, 0, stream>>>(xb, wqb, qkvpA, L_SEQ, QKV_N, DMODEL);

  // fused rope (20480 blocks) + V repack (512 blocks)
  rope_repack<<<20992, 256, 0, stream>>>(qkvpA, qkvpB, q_gamma, k_gamma, qb, kfr, vfr);

  flash_attn<<<640, 256, 0, stream>>>(qb, kfr, vfr, po, pl, ao);
  combine_split<<<768, 256, 0, stream>>>(po, pl, ao);

  gemm_bt<float><<<dim3(DMODEL / 64, L_SEQ / 128, 1), 128, 0, stream>>>(ao, wob, out, L_SEQ, DMODEL, DMODEL);
}